// Round 4
// baseline (334.984 us; speedup 1.0000x reference)
//
#include <hip/hip_runtime.h>
#include <hip/hip_cooperative_groups.h>
#include <math.h>

namespace cg = cooperative_groups;

// Problem constants (fixed by setup_inputs)
#define BSZ    2
#define LFULL  4096
#define MLEN   2048      // M = hidden_states.shape[1]
#define DMODEL 2048
#define CLIP_EPS 1e-4f
#define CCH    256       // number of chunks
#define TCH    8         // chunk length; CCH*TCH == MLEN
#define NBLK   (BSZ * CCH * 2)   // 1024 blocks; must be co-resident (4/CU)

typedef float f4 __attribute__((ext_vector_type(4)));

// ---------------------------------------------------------------------------
// K1: prep. One block per batch (grid = BSZ). Unchanged from R3 (passing).
// ---------------------------------------------------------------------------
__global__ __launch_bounds__(256) void k1_prep(
    const int* __restrict__ bmask_raw, const float* __restrict__ bprob,
    int* __restrict__ Ls, int* __restrict__ Le,
    float* __restrict__ wA, float* __restrict__ eA,
    float* __restrict__ cde, float* __restrict__ Pc)
{
  const int b   = blockIdx.x;
  const int tid = threadIdx.x;

  __shared__ int   s_cnt[257];
  __shared__ int   s_mode;
  __shared__ int   s_ntrue;
  __shared__ int   s_sel[MLEN];        // 8 KB
  __shared__ float s_e[MLEN];          // 8 KB

  if (tid == 0) {
    unsigned w0 = ((const unsigned*)bmask_raw)[0];
    s_mode = (w0 <= 1u) ? 1 : 0;  // 1: int32 per element, 0: uint8 per element
  }
  __syncthreads();
  const int mode = s_mode;
  const unsigned char* bmask_u8 = (const unsigned char*)bmask_raw;

  const int PER = LFULL / 256;    // 16 positions per thread
  const int base = tid * PER;

  int cnt = 0;
  for (int i = 0; i < PER; ++i) {
    const int L = base + i;
    const int v = mode ? (bmask_raw[b * LFULL + L] != 0)
                       : (bmask_u8[b * LFULL + L] != 0);
    cnt += v;
  }
  s_cnt[tid] = cnt;
  __syncthreads();
  if (tid == 0) {
    int acc = 0;
    for (int i = 0; i < 256; ++i) { int c = s_cnt[i]; s_cnt[i] = acc; acc += c; }
    s_cnt[256] = acc;
    s_ntrue = acc;
  }
  __syncthreads();
  const int ntrue = s_ntrue;

  // Fill sel: boundary positions (rank) then non-boundary (ntrue + false-rank)
  int trun = s_cnt[tid];
  for (int i = 0; i < PER; ++i) {
    const int L = base + i;
    const int v = mode ? (bmask_raw[b * LFULL + L] != 0)
                       : (bmask_u8[b * LFULL + L] != 0);
    if (v) {
      if (trun < MLEN) s_sel[trun] = L;
      ++trun;
    } else {
      const int f = L - trun;           // falses strictly before L
      const int slot = ntrue + f;
      if (slot < MLEN) s_sel[slot] = L;
    }
  }
  __syncthreads();

  // w, e per selected position
  for (int j = tid; j < MLEN; j += 256) {
    const int L = s_sel[j];
    float p = bprob[((size_t)b * LFULL + L) * 2 + 1];
    p = fminf(fmaxf(p, CLIP_EPS), 1.0f - CLIP_EPS);
    const float dt = -log1pf(-p);       // log(1/(1-p))
    wA[b * MLEN + j] = p / dt;
    const float e = 1.0f - p;           // exp(-dt) exactly
    eA[b * MLEN + j] = e;
    s_e[j] = e;
  }
  __syncthreads();

  // per-chunk cumulative decay + chunk product: one thread per chunk of 8
  {
    const int c = tid;                  // 256 chunks
    const int o = c * TCH;
    float run = 1.0f;
    #pragma unroll
    for (int i = 0; i < TCH; ++i) {
      run *= s_e[o + i];
      cde[b * MLEN + o + i] = run;
    }
    Pc[b * CCH + c] = run;
  }

  // scatter ranges: plug[L] = (#boundaries <= L) - 1, clamped to [0, M-1]
  const int nb = (ntrue < MLEN) ? ntrue : MLEN;
  for (int j = tid; j < MLEN; j += 256) {
    int ls, le;
    if (nb == 0) {
      ls = (j == 0) ? 0 : LFULL;
      le = (j == 0) ? LFULL : LFULL;
    } else if (j < nb) {
      ls = (j == 0) ? 0 : s_sel[j];
      le = (j == nb - 1) ? LFULL : s_sel[j + 1];
    } else {
      ls = LFULL; le = LFULL;           // empty
    }
    Ls[b * MLEN + j] = ls;
    Le[b * MLEN + j] = le;
  }
}

// ---------------------------------------------------------------------------
// Fused cooperative kernel: 1024 resident blocks, LDS persists across syncs.
//  Phase A (block -> (x, c, b)): read hid ONCE, local scan, y_loc[t] -> LDS,
//           chunk-final state -> S (global).
//  Phase B (block -> (d4, b)):  Hillis-Steele scan over 256 chunks in LDS,
//           exclusive carry-in -> G (global).
//  Phase C (same mapping as A): H from G, y = y_loc + cde*H, nontemporal
//           scatter to out rows [Ls, Le). No hid re-read, no recompute.
// ---------------------------------------------------------------------------
__global__ __launch_bounds__(256, 4) void k_fused(
    const float* __restrict__ hid, const float* __restrict__ wA,
    const float* __restrict__ eA, const float* __restrict__ cde,
    const float* __restrict__ Pc, const int* __restrict__ Ls,
    const int* __restrict__ Le, float* __restrict__ S,
    float* __restrict__ G, float* __restrict__ out)
{
  cg::grid_group grid = cg::this_grid();
  const int lid = blockIdx.x;
  const int tid = threadIdx.x;

  __shared__ f4    s_yloc[TCH * 256];   // 32 KB — persists A -> C
  __shared__ float s_scanP[CCH];        // 1 KB  — phase B scratch
  __shared__ f4    s_scanS[CCH];        // 4 KB  — phase B scratch
  __shared__ float s_w[TCH], s_e[TCH], s_c[TCH];
  __shared__ int   s_ls[TCH], s_le[TCH];

  // ---- Phase A mapping: x = half of d-range, c = chunk, b = batch
  const int xA = lid & 1;
  const int cA = (lid >> 1) & (CCH - 1);
  const int bA = lid >> 9;
  const int d4 = xA * 256 + tid;        // float4 lane in [0, 512)

  {
    const int o = bA * MLEN + cA * TCH;
    if (tid < TCH)          { s_w[tid] = wA[o + tid];  s_ls[tid] = Ls[o + tid]; }
    else if (tid < 2 * TCH) { const int t = tid - TCH;     s_e[t] = eA[o + t]; s_le[t] = Le[o + t]; }
    else if (tid < 3 * TCH) { const int t = tid - 2 * TCH; s_c[t] = cde[o + t]; }
  }
  __syncthreads();

  {
    const f4* xp = (const f4*)hid + ((size_t)(bA * MLEN + cA * TCH) * DMODEL >> 2) + d4;
    f4 st = {0.f, 0.f, 0.f, 0.f};
    #pragma unroll
    for (int t = 0; t < TCH; ++t) {
      const f4 xv = xp[(size_t)t * (DMODEL / 4)];
      const float w = s_w[t], e = s_e[t];
      st.x = fmaf(e, st.x, w * xv.x);
      st.y = fmaf(e, st.y, w * xv.y);
      st.z = fmaf(e, st.z, w * xv.z);
      st.w = fmaf(e, st.w, w * xv.w);
      s_yloc[t * 256 + tid] = st;
    }
    ((f4*)S)[((size_t)(bA * CCH + cA) * DMODEL >> 2) + d4] = st;
  }

  grid.sync();

  // ---- Phase B mapping: one block per (d4 column, batch)
  {
    const int d4b = lid & 511;
    const int bb  = lid >> 9;
    const int c   = tid;                // chunk index
    s_scanP[c] = Pc[bb * CCH + c];
    s_scanS[c] = ((const f4*)S)[((size_t)(bb * CCH + c) * DMODEL >> 2) + d4b];
    __syncthreads();

    #pragma unroll
    for (int dstep = 1; dstep < CCH; dstep <<= 1) {
      float pd = 1.0f;
      f4 sd = {0.f, 0.f, 0.f, 0.f};
      if (c >= dstep) { pd = s_scanP[c - dstep]; sd = s_scanS[c - dstep]; }
      __syncthreads();
      if (c >= dstep) {
        f4 cur = s_scanS[c];
        const float pc = s_scanP[c];
        cur.x = fmaf(pc, sd.x, cur.x);
        cur.y = fmaf(pc, sd.y, cur.y);
        cur.z = fmaf(pc, sd.z, cur.z);
        cur.w = fmaf(pc, sd.w, cur.w);
        s_scanS[c] = cur;
        s_scanP[c] = pc * pd;
      }
      __syncthreads();
    }

    // exclusive shift: carry-in for chunk c is inclusive scan at c-1
    f4 g = {0.f, 0.f, 0.f, 0.f};
    if (c > 0) g = s_scanS[c - 1];
    ((f4*)G)[((size_t)(bb * CCH + c) * DMODEL >> 2) + d4b] = g;
  }

  grid.sync();

  // ---- Phase C: same (xA, cA, bA) mapping; y_loc + staged params still in LDS
  {
    const f4 H = ((const f4*)G)[((size_t)(bA * CCH + cA) * DMODEL >> 2) + d4];
    f4* op = (f4*)out + ((size_t)bA * LFULL * DMODEL >> 2) + d4;
    #pragma unroll
    for (int t = 0; t < TCH; ++t) {
      const f4 st = s_yloc[t * 256 + tid];
      const float cd = s_c[t];
      f4 y;
      y.x = fmaf(cd, H.x, st.x);
      y.y = fmaf(cd, H.y, st.y);
      y.z = fmaf(cd, H.z, st.z);
      y.w = fmaf(cd, H.w, st.w);
      const int ls = s_ls[t], le = s_le[t];
      for (int L = ls; L < le; ++L) {
        __builtin_nontemporal_store(y, op + (size_t)L * (DMODEL / 4));
      }
    }
  }
}

// ---------------------------------------------------------------------------
extern "C" void kernel_launch(void* const* d_in, const int* in_sizes, int n_in,
                              void* d_out, int out_size, void* d_ws, size_t ws_size,
                              hipStream_t stream) {
  const float* hid   = (const float*)d_in[0];   // (2, 2048, 2048) fp32
  const int*   bmask = (const int*)d_in[1];     // (2, 4096) bool (layout sniffed)
  const float* bprob = (const float*)d_in[2];   // (2, 4096, 2) fp32
  float*       out   = (float*)d_out;           // (2, 4096, 2048) fp32

  char* ws = (char*)d_ws;
  const size_t SZI = (size_t)BSZ * MLEN * sizeof(int);    // 16 KB
  const size_t SZF = (size_t)BSZ * MLEN * sizeof(float);  // 16 KB
  int*   Ls  = (int*)(ws);
  int*   Le  = (int*)(ws + SZI);
  float* wA  = (float*)(ws + 2 * SZI);
  float* eA  = (float*)(ws + 2 * SZI + SZF);
  float* cde = (float*)(ws + 2 * SZI + 2 * SZF);
  float* Pc  = (float*)(ws + 2 * SZI + 3 * SZF);          // 2 KB used
  float* S   = (float*)(ws + 2 * SZI + 3 * SZF + 4096);           // 4 MB
  float* G   = (float*)(ws + 2 * SZI + 3 * SZF + 4096 + (size_t)4 * 1024 * 1024); // 4 MB

  k1_prep<<<dim3(BSZ), dim3(256), 0, stream>>>(bmask, bprob, Ls, Le, wA, eA, cde, Pc);

  void* args[] = { (void*)&hid, (void*)&wA, (void*)&eA, (void*)&cde, (void*)&Pc,
                   (void*)&Ls, (void*)&Le, (void*)&S, (void*)&G, (void*)&out };
  hipLaunchCooperativeKernel((const void*)k_fused, dim3(NBLK), dim3(256),
                             args, 0, stream);
}

// Round 5
// 127.785 us; speedup vs baseline: 2.6215x; 2.6215x over previous
//
#include <hip/hip_runtime.h>
#include <math.h>

// Problem constants (fixed by setup_inputs)
#define BSZ    2
#define LFULL  4096
#define MLEN   2048      // M = hidden_states.shape[1]
#define DMODEL 2048
#define CLIP_EPS 1e-4f
#define CCH    256       // number of chunks
#define TCH    8         // chunk length; CCH*TCH == MLEN

typedef float f4 __attribute__((ext_vector_type(4)));

// ---------------------------------------------------------------------------
// K1: prep. One block per batch (grid = BSZ).
//  - sniff boundary_mask dtype (int32 words vs packed uint8)
//  - stable-partition selection: sel[j] = j-th boundary position, then
//    non-boundary positions in order (argsort of idx + (!mask)*LFULL)
//  - p -> w = p/dt (dt = -log1p(-p)), e = 1-p  (== exp(-dt) exactly)
//  - per-chunk inclusive cumulative decay cde, chunk products Pc
//  - output scatter ranges [Ls[t], Le[t]) : all L with clamp(plug[L]) == t
//  NOTE: block-wide prefix scan done with a wave-0 shuffle scan (the old
//  serial thread-0 loop was ~2-3 us of pure latency).
// ---------------------------------------------------------------------------
__global__ __launch_bounds__(256) void k1_prep(
    const int* __restrict__ bmask_raw, const float* __restrict__ bprob,
    int* __restrict__ Ls, int* __restrict__ Le,
    float* __restrict__ wA, float* __restrict__ eA,
    float* __restrict__ cde, float* __restrict__ Pc)
{
  const int b   = blockIdx.x;
  const int tid = threadIdx.x;

  __shared__ int   s_cnt[257];
  __shared__ int   s_mode;
  __shared__ int   s_ntrue;
  __shared__ int   s_sel[MLEN];        // 8 KB
  __shared__ float s_e[MLEN];          // 8 KB

  if (tid == 0) {
    unsigned w0 = ((const unsigned*)bmask_raw)[0];
    s_mode = (w0 <= 1u) ? 1 : 0;  // 1: int32 per element, 0: uint8 per element
  }
  __syncthreads();
  const int mode = s_mode;
  const unsigned char* bmask_u8 = (const unsigned char*)bmask_raw;

  const int PER = LFULL / 256;    // 16 positions per thread
  const int base = tid * PER;

  int cnt = 0;
  for (int i = 0; i < PER; ++i) {
    const int L = base + i;
    const int v = mode ? (bmask_raw[b * LFULL + L] != 0)
                       : (bmask_u8[b * LFULL + L] != 0);
    cnt += v;
  }
  s_cnt[tid] = cnt;
  __syncthreads();

  // Exclusive prefix over 256 counts: wave 0, lane i owns entries 4i..4i+3.
  if (tid < 64) {
    const int j = tid * 4;
    const int c0 = s_cnt[j], c1 = s_cnt[j + 1], c2 = s_cnt[j + 2], c3 = s_cnt[j + 3];
    const int mysum = c0 + c1 + c2 + c3;
    int incl = mysum;
    #pragma unroll
    for (int off = 1; off < 64; off <<= 1) {
      const int v = __shfl_up(incl, off, 64);
      if (tid >= off) incl += v;
    }
    const int excl = incl - mysum;
    s_cnt[j]     = excl;
    s_cnt[j + 1] = excl + c0;
    s_cnt[j + 2] = excl + c0 + c1;
    s_cnt[j + 3] = excl + c0 + c1 + c2;
    if (tid == 63) { s_cnt[256] = incl; s_ntrue = incl; }
  }
  __syncthreads();
  const int ntrue = s_ntrue;

  // Fill sel: boundary positions (rank) then non-boundary (ntrue + false-rank)
  int trun = s_cnt[tid];
  for (int i = 0; i < PER; ++i) {
    const int L = base + i;
    const int v = mode ? (bmask_raw[b * LFULL + L] != 0)
                       : (bmask_u8[b * LFULL + L] != 0);
    if (v) {
      if (trun < MLEN) s_sel[trun] = L;
      ++trun;
    } else {
      const int f = L - trun;           // falses strictly before L
      const int slot = ntrue + f;
      if (slot < MLEN) s_sel[slot] = L;
    }
  }
  __syncthreads();

  // w, e per selected position
  for (int j = tid; j < MLEN; j += 256) {
    const int L = s_sel[j];
    float p = bprob[((size_t)b * LFULL + L) * 2 + 1];
    p = fminf(fmaxf(p, CLIP_EPS), 1.0f - CLIP_EPS);
    const float dt = -log1pf(-p);       // log(1/(1-p))
    wA[b * MLEN + j] = p / dt;
    const float e = 1.0f - p;           // exp(-dt) exactly
    eA[b * MLEN + j] = e;
    s_e[j] = e;
  }
  __syncthreads();

  // per-chunk cumulative decay + chunk product: one thread per chunk of 8
  {
    const int c = tid;                  // 256 chunks
    const int o = c * TCH;
    float run = 1.0f;
    #pragma unroll
    for (int i = 0; i < TCH; ++i) {
      run *= s_e[o + i];
      cde[b * MLEN + o + i] = run;
    }
    Pc[b * CCH + c] = run;
  }

  // scatter ranges: plug[L] = (#boundaries <= L) - 1, clamped to [0, M-1]
  const int nb = (ntrue < MLEN) ? ntrue : MLEN;
  for (int j = tid; j < MLEN; j += 256) {
    int ls, le;
    if (nb == 0) {
      ls = (j == 0) ? 0 : LFULL;
      le = (j == 0) ? LFULL : LFULL;
    } else if (j < nb) {
      ls = (j == 0) ? 0 : s_sel[j];
      le = (j == nb - 1) ? LFULL : s_sel[j + 1];
    } else {
      ls = LFULL; le = LFULL;           // empty
    }
    Ls[b * MLEN + j] = ls;
    Le[b * MLEN + j] = le;
  }
}

// ---------------------------------------------------------------------------
// K2: per-chunk local scan (zero init) -> chunk-final state S[b][c][d]
// grid: (DMODEL/1024, CCH, BSZ) = (2, 256, 2) = 1024 blocks, float4/thread
// ---------------------------------------------------------------------------
__global__ __launch_bounds__(256) void k2_states(
    const float* __restrict__ hid, const float* __restrict__ wA,
    const float* __restrict__ eA, float* __restrict__ S)
{
  const int tid = threadIdx.x;
  const int c = blockIdx.y;
  const int b = blockIdx.z;

  __shared__ float s_w[TCH], s_e[TCH];
  if (tid < TCH)            s_w[tid]       = wA[b * MLEN + c * TCH + tid];
  else if (tid < 2 * TCH)   s_e[tid - TCH] = eA[b * MLEN + c * TCH + (tid - TCH)];
  __syncthreads();

  const int d4 = blockIdx.x * 256 + tid;       // float4 lane in [0, 512)
  const f4* xp = (const f4*)hid + ((size_t)(b * MLEN + c * TCH) * DMODEL >> 2) + d4;

  f4 st = {0.f, 0.f, 0.f, 0.f};
  #pragma unroll
  for (int t = 0; t < TCH; ++t) {
    const f4 x = xp[(size_t)t * (DMODEL / 4)];
    const float w = s_w[t], e = s_e[t];
    st.x = fmaf(e, st.x, w * x.x);
    st.y = fmaf(e, st.y, w * x.y);
    st.z = fmaf(e, st.z, w * x.z);
    st.w = fmaf(e, st.w, w * x.w);
  }
  ((f4*)S)[((size_t)(b * CCH + c) * DMODEL >> 2) + d4] = st;
}

// ---------------------------------------------------------------------------
// K2.5: cross-chunk exclusive scan, in place over S.
//   G[c] = state entering chunk c:  G_inc[c] = Pc[c]*G_inc[c-1] + S[c]
//   One block per (d4 lane, batch); 256 threads = 256 chunks; Hillis-Steele.
// grid: (DMODEL/4, BSZ) = (512, 2) = 1024 blocks
// ---------------------------------------------------------------------------
__global__ __launch_bounds__(256) void k25_scan(
    const float* __restrict__ Pc, float* __restrict__ S)
{
  const int c  = threadIdx.x;   // chunk index
  const int d4 = blockIdx.x;    // float4 lane in [0, DMODEL/4)
  const int b  = blockIdx.y;

  __shared__ float sP[CCH];
  __shared__ f4    sS[CCH];

  f4* Sf4 = (f4*)S;
  const size_t idx = ((size_t)(b * CCH + c) * DMODEL >> 2) + d4;

  sP[c] = Pc[b * CCH + c];
  sS[c] = Sf4[idx];
  __syncthreads();

  #pragma unroll
  for (int dstep = 1; dstep < CCH; dstep <<= 1) {
    float pd = 1.0f;
    f4 sd = {0.f, 0.f, 0.f, 0.f};
    if (c >= dstep) { pd = sP[c - dstep]; sd = sS[c - dstep]; }
    __syncthreads();
    if (c >= dstep) {
      f4 cur = sS[c];
      const float pc = sP[c];
      cur.x = fmaf(pc, sd.x, cur.x);
      cur.y = fmaf(pc, sd.y, cur.y);
      cur.z = fmaf(pc, sd.z, cur.z);
      cur.w = fmaf(pc, sd.w, cur.w);
      sS[c] = cur;
      sP[c] = pc * pd;
    }
    __syncthreads();
  }

  // exclusive shift: carry-in for chunk c is inclusive scan at c-1
  f4 g = {0.f, 0.f, 0.f, 0.f};
  if (c > 0) g = sS[c - 1];
  Sf4[idx] = g;
}

// ---------------------------------------------------------------------------
// K3: load carry-in G, redo local scan, y = local + cde*G, scatter to
//     out rows [Ls, Le). Non-temporal stores (write-only 67 MB).
// grid: (2, CCH, BSZ) = 1024 blocks
// ---------------------------------------------------------------------------
__global__ __launch_bounds__(256) void k3_out(
    const float* __restrict__ hid, const float* __restrict__ wA,
    const float* __restrict__ eA, const float* __restrict__ cde,
    const float* __restrict__ G,
    const int* __restrict__ Ls, const int* __restrict__ Le,
    float* __restrict__ out)
{
  const int tid = threadIdx.x;
  const int c = blockIdx.y;
  const int b = blockIdx.z;

  __shared__ float s_w[TCH], s_e[TCH], s_c[TCH];
  __shared__ int   s_ls[TCH], s_le[TCH];
  const int o = b * MLEN + c * TCH;
  if (tid < TCH)          { s_w[tid] = wA[o + tid];  s_ls[tid] = Ls[o + tid]; }
  else if (tid < 2 * TCH) { const int t = tid - TCH;     s_e[t] = eA[o + t]; s_le[t] = Le[o + t]; }
  else if (tid < 3 * TCH) { const int t = tid - 2 * TCH; s_c[t] = cde[o + t]; }
  __syncthreads();

  const int d4 = blockIdx.x * 256 + tid;

  const f4 H = ((const f4*)G)[((size_t)(b * CCH + c) * DMODEL >> 2) + d4];

  const f4* xp = (const f4*)hid + ((size_t)(b * MLEN + c * TCH) * DMODEL >> 2) + d4;
  f4*       op = (f4*)out + ((size_t)b * LFULL * DMODEL >> 2) + d4;

  f4 st = {0.f, 0.f, 0.f, 0.f};
  #pragma unroll
  for (int t = 0; t < TCH; ++t) {
    const f4 x = xp[(size_t)t * (DMODEL / 4)];
    const float w = s_w[t], e = s_e[t], cd = s_c[t];
    st.x = fmaf(e, st.x, w * x.x);
    st.y = fmaf(e, st.y, w * x.y);
    st.z = fmaf(e, st.z, w * x.z);
    st.w = fmaf(e, st.w, w * x.w);
    f4 y;
    y.x = fmaf(cd, H.x, st.x);
    y.y = fmaf(cd, H.y, st.y);
    y.z = fmaf(cd, H.z, st.z);
    y.w = fmaf(cd, H.w, st.w);
    const int ls = s_ls[t], le = s_le[t];
    for (int L = ls; L < le; ++L) {
      __builtin_nontemporal_store(y, op + (size_t)L * (DMODEL / 4));
    }
  }
}

// ---------------------------------------------------------------------------
extern "C" void kernel_launch(void* const* d_in, const int* in_sizes, int n_in,
                              void* d_out, int out_size, void* d_ws, size_t ws_size,
                              hipStream_t stream) {
  const float* hid   = (const float*)d_in[0];   // (2, 2048, 2048) fp32
  const int*   bmask = (const int*)d_in[1];     // (2, 4096) bool (layout sniffed)
  const float* bprob = (const float*)d_in[2];   // (2, 4096, 2) fp32
  float*       out   = (float*)d_out;           // (2, 4096, 2048) fp32

  char* ws = (char*)d_ws;
  const size_t SZI = (size_t)BSZ * MLEN * sizeof(int);    // 16 KB
  const size_t SZF = (size_t)BSZ * MLEN * sizeof(float);  // 16 KB
  int*   Ls  = (int*)(ws);
  int*   Le  = (int*)(ws + SZI);
  float* wA  = (float*)(ws + 2 * SZI);
  float* eA  = (float*)(ws + 2 * SZI + SZF);
  float* cde = (float*)(ws + 2 * SZI + 2 * SZF);
  float* Pc  = (float*)(ws + 2 * SZI + 3 * SZF);          // 2 KB used
  float* S   = (float*)(ws + 2 * SZI + 3 * SZF + 4096);   // 4 MB (S, then G in place)

  k1_prep<<<dim3(BSZ), dim3(256), 0, stream>>>(bmask, bprob, Ls, Le, wA, eA, cde, Pc);

  dim3 grid(DMODEL / 1024, CCH, BSZ);   // (2, 256, 2) = 1024 blocks
  k2_states<<<grid, dim3(256), 0, stream>>>(hid, wA, eA, S);

  k25_scan<<<dim3(DMODEL / 4, BSZ), dim3(256), 0, stream>>>(Pc, S);

  k3_out<<<grid, dim3(256), 0, stream>>>(hid, wA, eA, cde, S, Ls, Le, out);
}